// Round 11
// baseline (144.861 us; speedup 1.0000x reference)
//
#include <hip/hip_runtime.h>
#include <hip/hip_bf16.h>

#define NPTS  4096
#define BATCH 4
#define KK    16
#define CH    64
#define SURV_CAP 64

typedef __attribute__((ext_vector_type(8))) short bf16x8;
typedef __attribute__((ext_vector_type(4))) float f32x4;

__device__ __forceinline__ unsigned short bhi(float x) {
    return (unsigned short)(__float_as_uint(x) >> 16);
}
__device__ __forceinline__ unsigned short blo(float x) {
    const float h = __uint_as_float(__float_as_uint(x) & 0xffff0000u);
    return (unsigned short)(__float_as_uint(x - h) >> 16);
}
__device__ __forceinline__ unsigned pk2(unsigned short a, unsigned short b) {
    return (unsigned)a | ((unsigned)b << 16);
}

// Reference-rounded squared distance: (mul,mul,mul,add,add), NO contraction.
__device__ __forceinline__ float ref_dist(float px, float py, float pz,
                                          float qx, float qy, float qz) {
#pragma clang fp contract(off)
    const float dx = px - qx, dy = py - qy, dz = pz - qz;
    const float sx = dx * dx, sy = dy * dy, sz = dz * dz;
    return (sx + sy) + sz;
}

// ---------------------------------------------------------------------------
// Kernel A: exact KNN, 2 queries per wave. SoA LDS staging (48KB x/y/z,
// |p|^2 recomputed per t) + sidx 4KB = 52KB -> 3 blocks/CU (was 68KB -> 1),
// raising waves/SIMD 2 -> 6 to hide the serial sort/compact chains.
// Selection logic identical to the round-9/10 passing version.
// ---------------------------------------------------------------------------
__global__ __launch_bounds__(512, 4) void knn_kernel(const float* __restrict__ xyz,
                                                     int* __restrict__ knn_idx) {
    __shared__ float sX[NPTS], sY[NPTS], sZ[NPTS];  // 48 KB SoA
    __shared__ int sidx[8][2][SURV_CAP];            // 4 KB survivor indices
    const int wave = threadIdx.x >> 6;
    const int lane = threadIdx.x & 63;
    const int q0 = blockIdx.x * 16 + wave * 2;      // queries q0, q0+1 (same batch)
    const int b = q0 >> 12;
    const int iA = q0 & (NPTS - 1), iB = iA + 1;
    const float* xb = xyz + (size_t)b * NPTS * 3;

    // ---- stage xyz -> LDS (SoA, stride-1 conflict-free) ----
#pragma unroll
    for (int r = 0; r < NPTS / 512; ++r) {
        const int pt = r * 512 + threadIdx.x;
        sX[pt] = xb[pt * 3 + 0];
        sY[pt] = xb[pt * 3 + 1];
        sZ[pt] = xb[pt * 3 + 2];
    }
    __syncthreads();

    const float qax = sX[iA], qay = sY[iA], qaz = sZ[iA];
    const float qbx = sX[iB], qby = sY[iB], qbz = sZ[iB];
    const float aAx = -2.f * qax, aAy = -2.f * qay, aAz = -2.f * qaz;
    const float aBx = -2.f * qbx, aBy = -2.f * qby, aBz = -2.f * qbz;

    // ---- approx keys (|p|^2 - 2 p.q, fma form) + per-lane mins ----
    float dA[64], dB[64];
    float mA = 3.4e38f, mB = 3.4e38f;
#pragma unroll
    for (int t = 0; t < 64; ++t) {
        const float px = sX[t * 64 + lane];
        const float py = sY[t * 64 + lane];
        const float pz = sZ[t * 64 + lane];
        const float w = fmaf(px, px, fmaf(py, py, pz * pz));
        const float sA = fmaf(pz, aAz, fmaf(py, aAy, fmaf(px, aAx, w)));
        const float sB = fmaf(pz, aBz, fmaf(py, aBy, fmaf(px, aBx, w)));
        dA[t] = sA; dB[t] = sB;
        mA = fminf(mA, sA); mB = fminf(mB, sB);
    }

    // ---- dual bitonic sort of lane minima ----
#pragma unroll
    for (int k = 2; k <= 64; k <<= 1) {
#pragma unroll
        for (int jj = k >> 1; jj > 0; jj >>= 1) {
            const float pA = __shfl_xor(mA, jj);
            const float pB = __shfl_xor(mB, jj);
            const bool tm = (((lane & jj) == 0) == ((lane & k) == 0));
            mA = ((pA < mA) == tm) ? pA : mA;
            mB = ((pB < mB) == tm) ? pB : mB;
        }
    }
    // 17th smallest lane-min + margin (covers approx-vs-exact rank error)
    const float TA = __shfl(mA, 16) + 1e-3f;
    const float TB = __shfl(mB, 16) + 1e-3f;

    // ---- ballot-compact survivor indices ----
    int baseA = 0, baseB = 0;
#pragma unroll
    for (int t = 0; t < 64; ++t) {
        {
            const bool sv = dA[t] <= TA;
            const unsigned long long mk = __ballot(sv);
            const int slot = baseA + __popcll(mk & ((1ull << lane) - 1ull));
            if (sv && slot < SURV_CAP) sidx[wave][0][slot] = t * 64 + lane;
            baseA += __popcll(mk);
        }
        {
            const bool sv = dB[t] <= TB;
            const unsigned long long mk = __ballot(sv);
            const int slot = baseB + __popcll(mk & ((1ull << lane) - 1ull));
            if (sv && slot < SURV_CAP) sidx[wave][1][slot] = t * 64 + lane;
            baseB += __popcll(mk);
        }
    }

    // ---- exact refine (reference rounding) for survivors ----
    unsigned long long keyA = ~0ull, keyB = ~0ull;
    if (lane < baseA && baseA <= SURV_CAP) {
        const int j = sidx[wave][0][lane];
        const float d = ref_dist(sX[j], sY[j], sZ[j], qax, qay, qaz);
        keyA = ((unsigned long long)__float_as_uint(d) << 32) | (unsigned)j;
    }
    if (lane < baseB && baseB <= SURV_CAP) {
        const int j = sidx[wave][1][lane];
        const float d = ref_dist(sX[j], sY[j], sZ[j], qbx, qby, qbz);
        keyB = ((unsigned long long)__float_as_uint(d) << 32) | (unsigned)j;
    }

    // ---- dual u64 bitonic sort == top_k (dist, index) order ----
#pragma unroll
    for (int k = 2; k <= 64; k <<= 1) {
#pragma unroll
        for (int jj = k >> 1; jj > 0; jj >>= 1) {
            const unsigned long long pA = __shfl_xor(keyA, jj);
            const unsigned long long pB = __shfl_xor(keyB, jj);
            const bool tm = (((lane & jj) == 0) == ((lane & k) == 0));
            keyA = ((pA < keyA) == tm) ? pA : keyA;
            keyB = ((pB < keyB) == tm) ? pB : keyB;
        }
    }

    // ---- exact fallback (correctness insurance; never runs on real data) --
    auto fallback = [&](int q, float qx, float qy, float qz) {
        float dp = -1.0f; int jp = -1;
        for (int pass = 0; pass < KK + 1; ++pass) {
            float dmin = 3.4e38f; int jmin = 0x7fffffff;
            for (int t = 0; t < 64; ++t) {
                const int j = t * 64 + lane;
                const float d = ref_dist(sX[j], sY[j], sZ[j], qx, qy, qz);
                const bool valid = (d > dp) || (d == dp && j > jp);
                const bool less = valid && (d < dmin || (d == dmin && j < jmin));
                dmin = less ? d : dmin;
                jmin = less ? j : jmin;
            }
#pragma unroll
            for (int off = 32; off > 0; off >>= 1) {
                const float d2 = __shfl_xor(dmin, off);
                const int   j2 = __shfl_xor(jmin, off);
                if (d2 < dmin || (d2 == dmin && j2 < jmin)) { dmin = d2; jmin = j2; }
            }
            if (pass >= 1 && lane == 0) knn_idx[(size_t)q * KK + pass - 1] = jmin;
            dp = dmin; jp = jmin;
        }
    };

    if (baseA <= SURV_CAP) {
        if (lane >= 1 && lane <= KK)
            knn_idx[(size_t)q0 * KK + lane - 1] = (int)(keyA & 0xffffffffu);
    } else fallback(q0, qax, qay, qaz);
    if (baseB <= SURV_CAP) {
        if (lane >= 1 && lane <= KK)
            knn_idx[(size_t)(q0 + 1) * KK + lane - 1] = (int)(keyB & 0xffffffffu);
    } else fallback(q0 + 1, qbx, qby, qbz);
}

// ---------------------------------------------------------------------------
// Kernel B v5: split-bf16 MFMA MLP (UNCHANGED from round-10 passing version).
// ---------------------------------------------------------------------------
__global__ __launch_bounds__(256, 2) void mlp_kernel(const float* __restrict__ xyz,
                                                     const int* __restrict__ knn_idx,
                                                     const float* __restrict__ w1,
                                                     const float* __restrict__ w2,
                                                     const float* __restrict__ w3,
                                                     float* __restrict__ out) {
    __shared__ __align__(16) unsigned short w2h[64 * 64], w2l[64 * 64];
    __shared__ __align__(16) unsigned short w3h[64 * 64], w3l[64 * 64];
    __shared__ __align__(16) unsigned short cbh[4][32 * 64], cbl[4][32 * 64];
    __shared__ __align__(16) float obuf[CH][36];   // stride 36: 16B-aligned rows

    const int tid = threadIdx.x;
    const int wave = tid >> 6, lane = tid & 63;
    const int lq = lane & 15, lg = lane >> 4;
    const int bx = blockIdx.x;
    const int bb = bx >> 7;                        // 128 blocks per batch
    const int nbase = (bx & 127) * 32;             // 32 points per block
    const float* xb = xyz + (size_t)bb * NPTS * 3;

    // ---- stage W2/W3 [64 rows][64 k] hi/lo, swizzle blk^(r&7) ----
    {
        const int r = tid >> 2, kb = (tid & 3) * 16;
#pragma unroll
        for (int kp = 0; kp < 16; kp += 2) {
            const int k = kb + kp;
            const float a0 = w2[r * 64 + k], a1 = w2[r * 64 + k + 1];
            const float c0 = w3[r * 64 + k], c1 = w3[r * 64 + k + 1];
            const int byt = r * 128 + (((k >> 3) ^ (r & 7)) << 4) + (k & 7) * 2;
            *(unsigned*)((char*)w2h + byt) = pk2(bhi(a0), bhi(a1));
            *(unsigned*)((char*)w2l + byt) = pk2(blo(a0), blo(a1));
            *(unsigned*)((char*)w3h + byt) = pk2(bhi(c0), bhi(c1));
            *(unsigned*)((char*)w3l + byt) = pk2(blo(c0), blo(c1));
        }
    }

    // ---- per-lane W1 rows for this lane's B-frag k-slots ----
    float w1v[2][8][3];
#pragma unroll
    for (int s = 0; s < 2; ++s)
#pragma unroll
        for (int j = 0; j < 8; ++j) {
            const int k = s * 32 + lg * 8 + j;
#pragma unroll
            for (int c = 0; c < 3; ++c) w1v[s][j][c] = w1[k * 3 + c];
        }

    // ---- prefetch all 4 groups' gathers (col = lane&31 owns one column) ----
    const int col = lane & 31;
    float gxa[4], gya[4], gza[4];
#pragma unroll
    for (int g = 0; g < 4; ++g) {
        const int n = nbase + g * 8 + wave * 2 + (col >> 4);
        const int j = knn_idx[((size_t)bb * NPTS + n) * KK + (col & 15)];
        gxa[g] = xb[j * 3 + 0] - xb[n * 3 + 0];
        gya[g] = xb[j * 3 + 1] - xb[n * 3 + 1];
        gza[g] = xb[j * 3 + 2] - xb[n * 3 + 2];
    }
    __syncthreads();   // weights staged

    unsigned short* const cbH = cbh[wave];
    unsigned short* const cbL = cbl[wave];

#pragma unroll
    for (int g = 0; g < 4; ++g) {
        // ---- layer 1 in VALU -> layer-2 B-frags (h1 split hi/lo) ----
        bf16x8 b1h[2][2], b1l[2][2];               // [s][t]
#pragma unroll
        for (int t = 0; t < 2; ++t) {
            const int src = t * 16 + lq;
            const float sgx = __shfl(gxa[g], src);
            const float sgy = __shfl(gya[g], src);
            const float sgz = __shfl(gza[g], src);
#pragma unroll
            for (int s = 0; s < 2; ++s) {
                bf16x8 hh, ll;
#pragma unroll
                for (int j = 0; j < 8; ++j) {
                    float v = fmaf(w1v[s][j][2], sgz,
                              fmaf(w1v[s][j][1], sgy, w1v[s][j][0] * sgx));
                    v = fmaxf(v, 0.f);
                    hh[j] = (short)bhi(v);
                    ll[j] = (short)blo(v);
                }
                b1h[s][t] = hh; b1l[s][t] = ll;
            }
        }

        // ---- layer 2: acc[m][t] = W2 . h1 (split-bf16, 48 MFMA) ----
        f32x4 acc[4][2];
#pragma unroll
        for (int m = 0; m < 4; ++m)
#pragma unroll
            for (int t = 0; t < 2; ++t) acc[m][t] = (f32x4){0.f, 0.f, 0.f, 0.f};
#pragma unroll
        for (int m = 0; m < 4; ++m) {
            const int r = m * 16 + lq;
#pragma unroll
            for (int s = 0; s < 2; ++s) {
                const int byt = r * 128 + (((s * 4 + lg) ^ (r & 7)) << 4);
                const bf16x8 ah = *(const bf16x8*)((const char*)w2h + byt);
                const bf16x8 al = *(const bf16x8*)((const char*)w2l + byt);
#pragma unroll
                for (int t = 0; t < 2; ++t) {
                    acc[m][t] = __builtin_amdgcn_mfma_f32_16x16x32_bf16(ah, b1h[s][t], acc[m][t], 0, 0, 0);
                    acc[m][t] = __builtin_amdgcn_mfma_f32_16x16x32_bf16(ah, b1l[s][t], acc[m][t], 0, 0, 0);
                    acc[m][t] = __builtin_amdgcn_mfma_f32_16x16x32_bf16(al, b1h[s][t], acc[m][t], 0, 0, 0);
                }
            }
        }

        // ---- relu(h2) split/pack -> per-wave colbuf [col][k] ----
#pragma unroll
        for (int m = 0; m < 4; ++m)
#pragma unroll
            for (int t = 0; t < 2; ++t) {
                f32x4 v = acc[m][t];
#pragma unroll
                for (int e = 0; e < 4; ++e) v[e] = fmaxf(v[e], 0.f);
                const int co = t * 16 + lq;
                const int k0 = m * 16 + lg * 4;
                const int byt = co * 128 + (((k0 >> 3) ^ (co & 7)) << 4) + (k0 & 7) * 2;
                uint2 hw, lw;
                hw.x = pk2(bhi(v[0]), bhi(v[1])); hw.y = pk2(bhi(v[2]), bhi(v[3]));
                lw.x = pk2(blo(v[0]), blo(v[1])); lw.y = pk2(blo(v[2]), blo(v[3]));
                *(uint2*)((char*)cbH + byt) = hw;
                *(uint2*)((char*)cbL + byt) = lw;
            }

        // ---- layer 3 transposed: D[nb][c3] = h2^T . w3-col (48 MFMA) ----
        bf16x8 xh[2][2], xl[2][2];                 // h2 A-frags [s][t]
#pragma unroll
        for (int s = 0; s < 2; ++s)
#pragma unroll
            for (int t = 0; t < 2; ++t) {
                const int co = t * 16 + lq;
                const int byt = co * 128 + (((s * 4 + lg) ^ (co & 7)) << 4);
                xh[s][t] = *(const bf16x8*)((const char*)cbH + byt);
                xl[s][t] = *(const bf16x8*)((const char*)cbL + byt);
            }
        f32x4 acc3[4][2];
#pragma unroll
        for (int mb = 0; mb < 4; ++mb)
#pragma unroll
            for (int t = 0; t < 2; ++t) acc3[mb][t] = (f32x4){0.f, 0.f, 0.f, 0.f};
#pragma unroll
        for (int mb = 0; mb < 4; ++mb) {
            const int r = mb * 16 + lq;
#pragma unroll
            for (int s = 0; s < 2; ++s) {
                const int byt = r * 128 + (((s * 4 + lg) ^ (r & 7)) << 4);
                const bf16x8 wh = *(const bf16x8*)((const char*)w3h + byt);
                const bf16x8 wl = *(const bf16x8*)((const char*)w3l + byt);
#pragma unroll
                for (int t = 0; t < 2; ++t) {
                    acc3[mb][t] = __builtin_amdgcn_mfma_f32_16x16x32_bf16(xh[s][t], wh, acc3[mb][t], 0, 0, 0);
                    acc3[mb][t] = __builtin_amdgcn_mfma_f32_16x16x32_bf16(xh[s][t], wl, acc3[mb][t], 0, 0, 0);
                    acc3[mb][t] = __builtin_amdgcn_mfma_f32_16x16x32_bf16(xl[s][t], wh, acc3[mb][t], 0, 0, 0);
                }
            }
        }

        // ---- max over neighbors (rows): 3 v_max + 2 shfl ----
#pragma unroll
        for (int mb = 0; mb < 4; ++mb)
#pragma unroll
            for (int t = 0; t < 2; ++t) {
                float v = fmaxf(fmaxf(acc3[mb][t][0], acc3[mb][t][1]),
                                fmaxf(acc3[mb][t][2], acc3[mb][t][3]));
                v = fmaxf(v, __shfl_xor(v, 16));
                v = fmaxf(v, __shfl_xor(v, 32));
                if (lg == 0) obuf[mb * 16 + lq][g * 8 + wave * 2 + t] = v;
            }
    }
    __syncthreads();

    // ---- coalesced store: 64 rows x 32 pts, 32B per thread ----
    {
        const int c = tid >> 2, seg = tid & 3;
        const float4 v0 = *(const float4*)&obuf[c][seg * 8];
        const float4 v1 = *(const float4*)&obuf[c][seg * 8 + 4];
        float* op = &out[((size_t)(bb * CH + c)) * NPTS + nbase + seg * 8];
        *(float4*)op = v0;
        *(float4*)(op + 4) = v1;
    }
}

extern "C" void kernel_launch(void* const* d_in, const int* in_sizes, int n_in,
                              void* d_out, int out_size, void* d_ws, size_t ws_size,
                              hipStream_t stream) {
    (void)in_sizes; (void)n_in; (void)out_size; (void)ws_size;
    const float* xyz = (const float*)d_in[0];
    const float* w1  = (const float*)d_in[1];
    const float* w2  = (const float*)d_in[2];
    const float* w3  = (const float*)d_in[3];
    int*   knn = (int*)d_ws;                 // BATCH*NPTS*KK ints = 1 MiB
    float* out = (float*)d_out;

    knn_kernel<<<BATCH * NPTS / 16, 512, 0, stream>>>(xyz, knn);
    mlp_kernel<<<BATCH * NPTS / 32, 256, 0, stream>>>(xyz, knn, w1, w2, w3, out);
}

// Round 13
// 114.691 us; speedup vs baseline: 1.2630x; 1.2630x over previous
//
#include <hip/hip_runtime.h>
#include <hip/hip_bf16.h>

#define NPTS  4096
#define BATCH 4
#define KK    16
#define CH    64
#define SURV_CAP 64

typedef __attribute__((ext_vector_type(8))) short bf16x8;
typedef __attribute__((ext_vector_type(4))) float f32x4;

__device__ __forceinline__ unsigned short bhi(float x) {
    return (unsigned short)(__float_as_uint(x) >> 16);
}
__device__ __forceinline__ unsigned short blo(float x) {
    const float h = __uint_as_float(__float_as_uint(x) & 0xffff0000u);
    return (unsigned short)(__float_as_uint(x - h) >> 16);
}
__device__ __forceinline__ unsigned pk2(unsigned short a, unsigned short b) {
    return (unsigned)a | ((unsigned)b << 16);
}

// Reference-rounded squared distance: (mul,mul,mul,add,add), NO contraction.
__device__ __forceinline__ float ref_dist(float px, float py, float pz,
                                          float qx, float qy, float qz) {
#pragma clang fp contract(off)
    const float dx = px - qx, dy = py - qy, dz = pz - qz;
    const float sx = dx * dx, sy = dy * dy, sz = dz * dz;
    return (sx + sy) + sz;
}

// ---------------------------------------------------------------------------
// Kernel A: exact KNN, 2 queries per wave, TWO-PASS (no d[64] arrays!).
// Round-11 lesson: dA[64]+dB[64] + launch_bounds VGPR cap 128 => scratch
// spill => 150MB HBM traffic. This version keeps only running minima in
// pass 1 and RECOMPUTES keys in pass 2 (identical fma sequence -> identical
// floats -> ballot matches threshold). Live regs ~25 -> no spill at cap 128.
// LDS: float2 xy + float z SoA (48KB) + sidx (4KB) = 52KB -> 3 blocks/CU.
// Selection semantics identical to the round-9/10 passing versions.
// ---------------------------------------------------------------------------
__global__ __launch_bounds__(512, 4) void knn_kernel(const float* __restrict__ xyz,
                                                     int* __restrict__ knn_idx) {
    __shared__ float2 sXY[NPTS];                    // 32 KB
    __shared__ float  sZ[NPTS];                     // 16 KB
    __shared__ int sidx[8][2][SURV_CAP];            // 4 KB survivor indices
    const int wave = threadIdx.x >> 6;
    const int lane = threadIdx.x & 63;
    const int q0 = blockIdx.x * 16 + wave * 2;      // queries q0, q0+1 (same batch)
    const int b = q0 >> 12;
    const int iA = q0 & (NPTS - 1), iB = iA + 1;
    const float* xb = xyz + (size_t)b * NPTS * 3;

    // ---- stage xyz -> LDS ----
#pragma unroll
    for (int r = 0; r < NPTS / 512; ++r) {
        const int pt = r * 512 + threadIdx.x;
        sXY[pt] = make_float2(xb[pt * 3 + 0], xb[pt * 3 + 1]);
        sZ[pt] = xb[pt * 3 + 2];
    }
    __syncthreads();

    const float2 qaXY = sXY[iA]; const float qaz = sZ[iA];
    const float2 qbXY = sXY[iB]; const float qbz = sZ[iB];
    const float qax = qaXY.x, qay = qaXY.y;
    const float qbx = qbXY.x, qby = qbXY.y;
    const float aAx = -2.f * qax, aAy = -2.f * qay, aAz = -2.f * qaz;
    const float aBx = -2.f * qbx, aBy = -2.f * qby, aBz = -2.f * qbz;

    // ---- pass 1: approx keys, track per-lane minima only ----
    float mA = 3.4e38f, mB = 3.4e38f;
#pragma unroll 8
    for (int t = 0; t < 64; ++t) {
        const float2 pxy = sXY[t * 64 + lane];
        const float pz = sZ[t * 64 + lane];
        const float px = pxy.x, py = pxy.y;
        const float w = fmaf(px, px, fmaf(py, py, pz * pz));
        const float sA = fmaf(pz, aAz, fmaf(py, aAy, fmaf(px, aAx, w)));
        const float sB = fmaf(pz, aBz, fmaf(py, aBy, fmaf(px, aBx, w)));
        mA = fminf(mA, sA); mB = fminf(mB, sB);
    }

    // ---- dual bitonic sort of lane minima ----
#pragma unroll
    for (int k = 2; k <= 64; k <<= 1) {
#pragma unroll
        for (int jj = k >> 1; jj > 0; jj >>= 1) {
            const float pA = __shfl_xor(mA, jj);
            const float pB = __shfl_xor(mB, jj);
            const bool tm = (((lane & jj) == 0) == ((lane & k) == 0));
            mA = ((pA < mA) == tm) ? pA : mA;
            mB = ((pB < mB) == tm) ? pB : mB;
        }
    }
    // 17th smallest lane-min + margin (covers approx-vs-exact rank error)
    const float TA = __shfl(mA, 16) + 1e-3f;
    const float TB = __shfl(mB, 16) + 1e-3f;

    // ---- pass 2: recompute keys (identical fma sequence), compact ----
    int baseA = 0, baseB = 0;
#pragma unroll 4
    for (int t = 0; t < 64; ++t) {
        const float2 pxy = sXY[t * 64 + lane];
        const float pz = sZ[t * 64 + lane];
        const float px = pxy.x, py = pxy.y;
        const float w = fmaf(px, px, fmaf(py, py, pz * pz));
        const float sA = fmaf(pz, aAz, fmaf(py, aAy, fmaf(px, aAx, w)));
        const float sB = fmaf(pz, aBz, fmaf(py, aBy, fmaf(px, aBx, w)));
        {
            const bool sv = sA <= TA;
            const unsigned long long mk = __ballot(sv);
            const int slot = baseA + __popcll(mk & ((1ull << lane) - 1ull));
            if (sv && slot < SURV_CAP) sidx[wave][0][slot] = t * 64 + lane;
            baseA += __popcll(mk);
        }
        {
            const bool sv = sB <= TB;
            const unsigned long long mk = __ballot(sv);
            const int slot = baseB + __popcll(mk & ((1ull << lane) - 1ull));
            if (sv && slot < SURV_CAP) sidx[wave][1][slot] = t * 64 + lane;
            baseB += __popcll(mk);
        }
    }

    // ---- exact refine (reference rounding) for survivors ----
    unsigned long long keyA = ~0ull, keyB = ~0ull;
    if (lane < baseA && baseA <= SURV_CAP) {
        const int j = sidx[wave][0][lane];
        const float2 pxy = sXY[j];
        const float d = ref_dist(pxy.x, pxy.y, sZ[j], qax, qay, qaz);
        keyA = ((unsigned long long)__float_as_uint(d) << 32) | (unsigned)j;
    }
    if (lane < baseB && baseB <= SURV_CAP) {
        const int j = sidx[wave][1][lane];
        const float2 pxy = sXY[j];
        const float d = ref_dist(pxy.x, pxy.y, sZ[j], qbx, qby, qbz);
        keyB = ((unsigned long long)__float_as_uint(d) << 32) | (unsigned)j;
    }

    // ---- dual u64 bitonic sort == top_k (dist, index) order ----
#pragma unroll
    for (int k = 2; k <= 64; k <<= 1) {
#pragma unroll
        for (int jj = k >> 1; jj > 0; jj >>= 1) {
            const unsigned long long pA = __shfl_xor(keyA, jj);
            const unsigned long long pB = __shfl_xor(keyB, jj);
            const bool tm = (((lane & jj) == 0) == ((lane & k) == 0));
            keyA = ((pA < keyA) == tm) ? pA : keyA;
            keyB = ((pB < keyB) == tm) ? pB : keyB;
        }
    }

    // ---- exact fallback (correctness insurance; never runs on real data) --
    auto fallback = [&](int q, float qx, float qy, float qz) {
        float dp = -1.0f; int jp = -1;
        for (int pass = 0; pass < KK + 1; ++pass) {
            float dmin = 3.4e38f; int jmin = 0x7fffffff;
            for (int t = 0; t < 64; ++t) {
                const int j = t * 64 + lane;
                const float2 pxy = sXY[j];
                const float d = ref_dist(pxy.x, pxy.y, sZ[j], qx, qy, qz);
                const bool valid = (d > dp) || (d == dp && j > jp);
                const bool less = valid && (d < dmin || (d == dmin && j < jmin));
                dmin = less ? d : dmin;
                jmin = less ? j : jmin;
            }
#pragma unroll
            for (int off = 32; off > 0; off >>= 1) {
                const float d2 = __shfl_xor(dmin, off);
                const int   j2 = __shfl_xor(jmin, off);
                if (d2 < dmin || (d2 == dmin && j2 < jmin)) { dmin = d2; jmin = j2; }
            }
            if (pass >= 1 && lane == 0) knn_idx[(size_t)q * KK + pass - 1] = jmin;
            dp = dmin; jp = jmin;
        }
    };

    if (baseA <= SURV_CAP) {
        if (lane >= 1 && lane <= KK)
            knn_idx[(size_t)q0 * KK + lane - 1] = (int)(keyA & 0xffffffffu);
    } else fallback(q0, qax, qay, qaz);
    if (baseB <= SURV_CAP) {
        if (lane >= 1 && lane <= KK)
            knn_idx[(size_t)(q0 + 1) * KK + lane - 1] = (int)(keyB & 0xffffffffu);
    } else fallback(q0 + 1, qbx, qby, qbz);
}

// ---------------------------------------------------------------------------
// Kernel B v5: split-bf16 MFMA MLP (UNCHANGED from round-10/11 passing version).
// ---------------------------------------------------------------------------
__global__ __launch_bounds__(256, 2) void mlp_kernel(const float* __restrict__ xyz,
                                                     const int* __restrict__ knn_idx,
                                                     const float* __restrict__ w1,
                                                     const float* __restrict__ w2,
                                                     const float* __restrict__ w3,
                                                     float* __restrict__ out) {
    __shared__ __align__(16) unsigned short w2h[64 * 64], w2l[64 * 64];
    __shared__ __align__(16) unsigned short w3h[64 * 64], w3l[64 * 64];
    __shared__ __align__(16) unsigned short cbh[4][32 * 64], cbl[4][32 * 64];
    __shared__ __align__(16) float obuf[CH][36];   // stride 36: 16B-aligned rows

    const int tid = threadIdx.x;
    const int wave = tid >> 6, lane = tid & 63;
    const int lq = lane & 15, lg = lane >> 4;
    const int bx = blockIdx.x;
    const int bb = bx >> 7;                        // 128 blocks per batch
    const int nbase = (bx & 127) * 32;             // 32 points per block
    const float* xb = xyz + (size_t)bb * NPTS * 3;

    // ---- stage W2/W3 [64 rows][64 k] hi/lo, swizzle blk^(r&7) ----
    {
        const int r = tid >> 2, kb = (tid & 3) * 16;
#pragma unroll
        for (int kp = 0; kp < 16; kp += 2) {
            const int k = kb + kp;
            const float a0 = w2[r * 64 + k], a1 = w2[r * 64 + k + 1];
            const float c0 = w3[r * 64 + k], c1 = w3[r * 64 + k + 1];
            const int byt = r * 128 + (((k >> 3) ^ (r & 7)) << 4) + (k & 7) * 2;
            *(unsigned*)((char*)w2h + byt) = pk2(bhi(a0), bhi(a1));
            *(unsigned*)((char*)w2l + byt) = pk2(blo(a0), blo(a1));
            *(unsigned*)((char*)w3h + byt) = pk2(bhi(c0), bhi(c1));
            *(unsigned*)((char*)w3l + byt) = pk2(blo(c0), blo(c1));
        }
    }

    // ---- per-lane W1 rows for this lane's B-frag k-slots ----
    float w1v[2][8][3];
#pragma unroll
    for (int s = 0; s < 2; ++s)
#pragma unroll
        for (int j = 0; j < 8; ++j) {
            const int k = s * 32 + lg * 8 + j;
#pragma unroll
            for (int c = 0; c < 3; ++c) w1v[s][j][c] = w1[k * 3 + c];
        }

    // ---- prefetch all 4 groups' gathers (col = lane&31 owns one column) ----
    const int col = lane & 31;
    float gxa[4], gya[4], gza[4];
#pragma unroll
    for (int g = 0; g < 4; ++g) {
        const int n = nbase + g * 8 + wave * 2 + (col >> 4);
        const int j = knn_idx[((size_t)bb * NPTS + n) * KK + (col & 15)];
        gxa[g] = xb[j * 3 + 0] - xb[n * 3 + 0];
        gya[g] = xb[j * 3 + 1] - xb[n * 3 + 1];
        gza[g] = xb[j * 3 + 2] - xb[n * 3 + 2];
    }
    __syncthreads();   // weights staged

    unsigned short* const cbH = cbh[wave];
    unsigned short* const cbL = cbl[wave];

#pragma unroll
    for (int g = 0; g < 4; ++g) {
        // ---- layer 1 in VALU -> layer-2 B-frags (h1 split hi/lo) ----
        bf16x8 b1h[2][2], b1l[2][2];               // [s][t]
#pragma unroll
        for (int t = 0; t < 2; ++t) {
            const int src = t * 16 + lq;
            const float sgx = __shfl(gxa[g], src);
            const float sgy = __shfl(gya[g], src);
            const float sgz = __shfl(gza[g], src);
#pragma unroll
            for (int s = 0; s < 2; ++s) {
                bf16x8 hh, ll;
#pragma unroll
                for (int j = 0; j < 8; ++j) {
                    float v = fmaf(w1v[s][j][2], sgz,
                              fmaf(w1v[s][j][1], sgy, w1v[s][j][0] * sgx));
                    v = fmaxf(v, 0.f);
                    hh[j] = (short)bhi(v);
                    ll[j] = (short)blo(v);
                }
                b1h[s][t] = hh; b1l[s][t] = ll;
            }
        }

        // ---- layer 2: acc[m][t] = W2 . h1 (split-bf16, 48 MFMA) ----
        f32x4 acc[4][2];
#pragma unroll
        for (int m = 0; m < 4; ++m)
#pragma unroll
            for (int t = 0; t < 2; ++t) acc[m][t] = (f32x4){0.f, 0.f, 0.f, 0.f};
#pragma unroll
        for (int m = 0; m < 4; ++m) {
            const int r = m * 16 + lq;
#pragma unroll
            for (int s = 0; s < 2; ++s) {
                const int byt = r * 128 + (((s * 4 + lg) ^ (r & 7)) << 4);
                const bf16x8 ah = *(const bf16x8*)((const char*)w2h + byt);
                const bf16x8 al = *(const bf16x8*)((const char*)w2l + byt);
#pragma unroll
                for (int t = 0; t < 2; ++t) {
                    acc[m][t] = __builtin_amdgcn_mfma_f32_16x16x32_bf16(ah, b1h[s][t], acc[m][t], 0, 0, 0);
                    acc[m][t] = __builtin_amdgcn_mfma_f32_16x16x32_bf16(ah, b1l[s][t], acc[m][t], 0, 0, 0);
                    acc[m][t] = __builtin_amdgcn_mfma_f32_16x16x32_bf16(al, b1h[s][t], acc[m][t], 0, 0, 0);
                }
            }
        }

        // ---- relu(h2) split/pack -> per-wave colbuf [col][k] ----
#pragma unroll
        for (int m = 0; m < 4; ++m)
#pragma unroll
            for (int t = 0; t < 2; ++t) {
                f32x4 v = acc[m][t];
#pragma unroll
                for (int e = 0; e < 4; ++e) v[e] = fmaxf(v[e], 0.f);
                const int co = t * 16 + lq;
                const int k0 = m * 16 + lg * 4;
                const int byt = co * 128 + (((k0 >> 3) ^ (co & 7)) << 4) + (k0 & 7) * 2;
                uint2 hw, lw;
                hw.x = pk2(bhi(v[0]), bhi(v[1])); hw.y = pk2(bhi(v[2]), bhi(v[3]));
                lw.x = pk2(blo(v[0]), blo(v[1])); lw.y = pk2(blo(v[2]), blo(v[3]));
                *(uint2*)((char*)cbH + byt) = hw;
                *(uint2*)((char*)cbL + byt) = lw;
            }

        // ---- layer 3 transposed: D[nb][c3] = h2^T . w3-col (48 MFMA) ----
        bf16x8 xh[2][2], xl[2][2];                 // h2 A-frags [s][t]
#pragma unroll
        for (int s = 0; s < 2; ++s)
#pragma unroll
            for (int t = 0; t < 2; ++t) {
                const int co = t * 16 + lq;
                const int byt = co * 128 + (((s * 4 + lg) ^ (co & 7)) << 4);
                xh[s][t] = *(const bf16x8*)((const char*)cbH + byt);
                xl[s][t] = *(const bf16x8*)((const char*)cbL + byt);
            }
        f32x4 acc3[4][2];
#pragma unroll
        for (int mb = 0; mb < 4; ++mb)
#pragma unroll
            for (int t = 0; t < 2; ++t) acc3[mb][t] = (f32x4){0.f, 0.f, 0.f, 0.f};
#pragma unroll
        for (int mb = 0; mb < 4; ++mb) {
            const int r = mb * 16 + lq;
#pragma unroll
            for (int s = 0; s < 2; ++s) {
                const int byt = r * 128 + (((s * 4 + lg) ^ (r & 7)) << 4);
                const bf16x8 wh = *(const bf16x8*)((const char*)w3h + byt);
                const bf16x8 wl = *(const bf16x8*)((const char*)w3l + byt);
#pragma unroll
                for (int t = 0; t < 2; ++t) {
                    acc3[mb][t] = __builtin_amdgcn_mfma_f32_16x16x32_bf16(xh[s][t], wh, acc3[mb][t], 0, 0, 0);
                    acc3[mb][t] = __builtin_amdgcn_mfma_f32_16x16x32_bf16(xh[s][t], wl, acc3[mb][t], 0, 0, 0);
                    acc3[mb][t] = __builtin_amdgcn_mfma_f32_16x16x32_bf16(xl[s][t], wh, acc3[mb][t], 0, 0, 0);
                }
            }
        }

        // ---- max over neighbors (rows): 3 v_max + 2 shfl ----
#pragma unroll
        for (int mb = 0; mb < 4; ++mb)
#pragma unroll
            for (int t = 0; t < 2; ++t) {
                float v = fmaxf(fmaxf(acc3[mb][t][0], acc3[mb][t][1]),
                                fmaxf(acc3[mb][t][2], acc3[mb][t][3]));
                v = fmaxf(v, __shfl_xor(v, 16));
                v = fmaxf(v, __shfl_xor(v, 32));
                if (lg == 0) obuf[mb * 16 + lq][g * 8 + wave * 2 + t] = v;
            }
    }
    __syncthreads();

    // ---- coalesced store: 64 rows x 32 pts, 32B per thread ----
    {
        const int c = tid >> 2, seg = tid & 3;
        const float4 v0 = *(const float4*)&obuf[c][seg * 8];
        const float4 v1 = *(const float4*)&obuf[c][seg * 8 + 4];
        float* op = &out[((size_t)(bb * CH + c)) * NPTS + nbase + seg * 8];
        *(float4*)op = v0;
        *(float4*)(op + 4) = v1;
    }
}

extern "C" void kernel_launch(void* const* d_in, const int* in_sizes, int n_in,
                              void* d_out, int out_size, void* d_ws, size_t ws_size,
                              hipStream_t stream) {
    (void)in_sizes; (void)n_in; (void)out_size; (void)ws_size;
    const float* xyz = (const float*)d_in[0];
    const float* w1  = (const float*)d_in[1];
    const float* w2  = (const float*)d_in[2];
    const float* w3  = (const float*)d_in[3];
    int*   knn = (int*)d_ws;                 // BATCH*NPTS*KK ints = 1 MiB
    float* out = (float*)d_out;

    knn_kernel<<<BATCH * NPTS / 16, 512, 0, stream>>>(xyz, knn);
    mlp_kernel<<<BATCH * NPTS / 32, 256, 0, stream>>>(xyz, knn, w1, w2, w3, out);
}

// Round 14
// 106.628 us; speedup vs baseline: 1.3586x; 1.0756x over previous
//
#include <hip/hip_runtime.h>
#include <hip/hip_bf16.h>

#define NPTS  4096
#define BATCH 4
#define KK    16
#define CH    64
#define SURV_CAP 40

typedef __attribute__((ext_vector_type(8))) short bf16x8;
typedef __attribute__((ext_vector_type(4))) float f32x4;

__device__ __forceinline__ unsigned short bhi(float x) {
    return (unsigned short)(__float_as_uint(x) >> 16);
}
__device__ __forceinline__ unsigned short blo(float x) {
    const float h = __uint_as_float(__float_as_uint(x) & 0xffff0000u);
    return (unsigned short)(__float_as_uint(x - h) >> 16);
}
__device__ __forceinline__ unsigned pk2(unsigned short a, unsigned short b) {
    return (unsigned)a | ((unsigned)b << 16);
}

// Reference-rounded squared distance: (mul,mul,mul,add,add), NO contraction.
__device__ __forceinline__ float ref_dist(float px, float py, float pz,
                                          float qx, float qy, float qz) {
#pragma clang fp contract(off)
    const float dx = px - qx, dy = py - qy, dz = pz - qz;
    const float sx = dx * dx, sy = dy * dy, sz = dz * dz;
    return (sx + sy) + sz;
}

// ---------------------------------------------------------------------------
// Kernel A: exact KNN, 4 queries per wave, two-pass, atomic-append compact.
//  * Pass 1: approx keys s~ = |p|^2 - 2 p.q (fma), per-lane minima only (no
//    d[64] arrays -> no spill; R11 lesson). Quad-interleaved bitonic sort of
//    lane minima -> T[v] = 17th smallest + 1e-3 margin (provable superset of
//    the reference top-17: approx-vs-exact rank error <= ~6e-5).
//  * Pass 2: recompute keys (identical fma sequence -> bit-identical) and
//    append survivor indices via per-wave LDS atomicAdd. Slot ORDER is
//    irrelevant: the final u64 (d_bits<<32|j) bitonic sort fully determines
//    top_k's (dist, index) order. Count is exact -> >CAP falls back to the
//    exact successive-min (correctness never depends on the pivot).
//  * Exact refine for survivors uses ref_dist (reference rounding).
// LDS: 48KB points SoA + 5.1KB sidx + cnt = ~54.5KB -> 3 blocks/CU.
// ---------------------------------------------------------------------------
__global__ __launch_bounds__(512, 4) void knn_kernel(const float* __restrict__ xyz,
                                                     int* __restrict__ knn_idx) {
    __shared__ float2 sXY[NPTS];                    // 32 KB
    __shared__ float  sZ[NPTS];                     // 16 KB
    __shared__ int sidx[8][4][SURV_CAP];            // 5 KB survivor indices
    __shared__ int scnt[8][4];                      // per-wave survivor counts
    const int wave = threadIdx.x >> 6;
    const int lane = threadIdx.x & 63;
    const int q0 = blockIdx.x * 32 + wave * 4;      // queries q0..q0+3 (same batch)
    const int b = q0 >> 12;
    const int i0 = q0 & (NPTS - 1);
    const float* xb = xyz + (size_t)b * NPTS * 3;

    // ---- stage xyz -> LDS (SoA) ----
#pragma unroll
    for (int r = 0; r < NPTS / 512; ++r) {
        const int pt = r * 512 + threadIdx.x;
        sXY[pt] = make_float2(xb[pt * 3 + 0], xb[pt * 3 + 1]);
        sZ[pt] = xb[pt * 3 + 2];
    }
    if (lane < 4) scnt[wave][lane] = 0;             // per-wave, DS in-order
    __syncthreads();

    float qx[4], qy[4], qz[4], ax[4], ay[4], az[4];
#pragma unroll
    for (int v = 0; v < 4; ++v) {
        const float2 t = sXY[i0 + v];
        qx[v] = t.x; qy[v] = t.y; qz[v] = sZ[i0 + v];
        ax[v] = -2.f * qx[v]; ay[v] = -2.f * qy[v]; az[v] = -2.f * qz[v];
    }

    // ---- pass 1: approx keys, per-lane minima only ----
    float mn[4] = {3.4e38f, 3.4e38f, 3.4e38f, 3.4e38f};
#pragma unroll 8
    for (int t = 0; t < 64; ++t) {
        const float2 pxy = sXY[t * 64 + lane];
        const float pz = sZ[t * 64 + lane];
        const float px = pxy.x, py = pxy.y;
        const float w = fmaf(px, px, fmaf(py, py, pz * pz));
#pragma unroll
        for (int v = 0; v < 4; ++v) {
            const float s = fmaf(pz, az[v], fmaf(py, ay[v], fmaf(px, ax[v], w)));
            mn[v] = fminf(mn[v], s);
        }
    }

    // ---- quad-interleaved bitonic sort of lane minima ----
#pragma unroll
    for (int k = 2; k <= 64; k <<= 1) {
#pragma unroll
        for (int jj = k >> 1; jj > 0; jj >>= 1) {
            const bool tm = (((lane & jj) == 0) == ((lane & k) == 0));
#pragma unroll
            for (int v = 0; v < 4; ++v) {
                const float p = __shfl_xor(mn[v], jj);
                mn[v] = ((p < mn[v]) == tm) ? p : mn[v];
            }
        }
    }
    float T[4];
#pragma unroll
    for (int v = 0; v < 4; ++v) T[v] = __shfl(mn[v], 16) + 1e-3f;

    // ---- pass 2: recompute keys (bit-identical), atomic-append survivors --
#pragma unroll 4
    for (int t = 0; t < 64; ++t) {
        const float2 pxy = sXY[t * 64 + lane];
        const float pz = sZ[t * 64 + lane];
        const float px = pxy.x, py = pxy.y;
        const float w = fmaf(px, px, fmaf(py, py, pz * pz));
#pragma unroll
        for (int v = 0; v < 4; ++v) {
            const float s = fmaf(pz, az[v], fmaf(py, ay[v], fmaf(px, ax[v], w)));
            if (s <= T[v]) {
                const int slot = atomicAdd(&scnt[wave][v], 1);
                if (slot < SURV_CAP) sidx[wave][v][slot] = t * 64 + lane;
            }
        }
    }
    int cnt[4];
#pragma unroll
    for (int v = 0; v < 4; ++v) cnt[v] = scnt[wave][v];  // wave DS in-order

    // ---- exact refine (reference rounding) for survivors ----
    unsigned long long key[4];
#pragma unroll
    for (int v = 0; v < 4; ++v) {
        key[v] = ~0ull;
        if (lane < cnt[v] && cnt[v] <= SURV_CAP) {
            const int j = sidx[wave][v][lane];
            const float2 pxy = sXY[j];
            const float d = ref_dist(pxy.x, pxy.y, sZ[j], qx[v], qy[v], qz[v]);
            key[v] = ((unsigned long long)__float_as_uint(d) << 32) | (unsigned)j;
        }
    }

    // ---- quad u64 bitonic sort == top_k (dist, index) order ----
#pragma unroll
    for (int k = 2; k <= 64; k <<= 1) {
#pragma unroll
        for (int jj = k >> 1; jj > 0; jj >>= 1) {
            const bool tm = (((lane & jj) == 0) == ((lane & k) == 0));
#pragma unroll
            for (int v = 0; v < 4; ++v) {
                const unsigned long long p = __shfl_xor(key[v], jj);
                key[v] = ((p < key[v]) == tm) ? p : key[v];
            }
        }
    }

    // ---- exact fallback (correctness insurance; never runs on real data) --
    auto fallback = [&](int q, float fqx, float fqy, float fqz) {
        float dp = -1.0f; int jp = -1;
        for (int pass = 0; pass < KK + 1; ++pass) {
            float dmin = 3.4e38f; int jmin = 0x7fffffff;
            for (int t = 0; t < 64; ++t) {
                const int j = t * 64 + lane;
                const float2 pxy = sXY[j];
                const float d = ref_dist(pxy.x, pxy.y, sZ[j], fqx, fqy, fqz);
                const bool valid = (d > dp) || (d == dp && j > jp);
                const bool less = valid && (d < dmin || (d == dmin && j < jmin));
                dmin = less ? d : dmin;
                jmin = less ? j : jmin;
            }
#pragma unroll
            for (int off = 32; off > 0; off >>= 1) {
                const float d2 = __shfl_xor(dmin, off);
                const int   j2 = __shfl_xor(jmin, off);
                if (d2 < dmin || (d2 == dmin && j2 < jmin)) { dmin = d2; jmin = j2; }
            }
            if (pass >= 1 && lane == 0) knn_idx[(size_t)q * KK + pass - 1] = jmin;
            dp = dmin; jp = jmin;
        }
    };

#pragma unroll
    for (int v = 0; v < 4; ++v) {
        if (cnt[v] <= SURV_CAP) {
            if (lane >= 1 && lane <= KK)
                knn_idx[(size_t)(q0 + v) * KK + lane - 1] = (int)(key[v] & 0xffffffffu);
        } else fallback(q0 + v, qx[v], qy[v], qz[v]);
    }
}

// ---------------------------------------------------------------------------
// Kernel B v5: split-bf16 MFMA MLP (UNCHANGED from round-10/13 passing version).
// ---------------------------------------------------------------------------
__global__ __launch_bounds__(256, 2) void mlp_kernel(const float* __restrict__ xyz,
                                                     const int* __restrict__ knn_idx,
                                                     const float* __restrict__ w1,
                                                     const float* __restrict__ w2,
                                                     const float* __restrict__ w3,
                                                     float* __restrict__ out) {
    __shared__ __align__(16) unsigned short w2h[64 * 64], w2l[64 * 64];
    __shared__ __align__(16) unsigned short w3h[64 * 64], w3l[64 * 64];
    __shared__ __align__(16) unsigned short cbh[4][32 * 64], cbl[4][32 * 64];
    __shared__ __align__(16) float obuf[CH][36];   // stride 36: 16B-aligned rows

    const int tid = threadIdx.x;
    const int wave = tid >> 6, lane = tid & 63;
    const int lq = lane & 15, lg = lane >> 4;
    const int bx = blockIdx.x;
    const int bb = bx >> 7;                        // 128 blocks per batch
    const int nbase = (bx & 127) * 32;             // 32 points per block
    const float* xb = xyz + (size_t)bb * NPTS * 3;

    // ---- stage W2/W3 [64 rows][64 k] hi/lo, swizzle blk^(r&7) ----
    {
        const int r = tid >> 2, kb = (tid & 3) * 16;
#pragma unroll
        for (int kp = 0; kp < 16; kp += 2) {
            const int k = kb + kp;
            const float a0 = w2[r * 64 + k], a1 = w2[r * 64 + k + 1];
            const float c0 = w3[r * 64 + k], c1 = w3[r * 64 + k + 1];
            const int byt = r * 128 + (((k >> 3) ^ (r & 7)) << 4) + (k & 7) * 2;
            *(unsigned*)((char*)w2h + byt) = pk2(bhi(a0), bhi(a1));
            *(unsigned*)((char*)w2l + byt) = pk2(blo(a0), blo(a1));
            *(unsigned*)((char*)w3h + byt) = pk2(bhi(c0), bhi(c1));
            *(unsigned*)((char*)w3l + byt) = pk2(blo(c0), blo(c1));
        }
    }

    // ---- per-lane W1 rows for this lane's B-frag k-slots ----
    float w1v[2][8][3];
#pragma unroll
    for (int s = 0; s < 2; ++s)
#pragma unroll
        for (int j = 0; j < 8; ++j) {
            const int k = s * 32 + lg * 8 + j;
#pragma unroll
            for (int c = 0; c < 3; ++c) w1v[s][j][c] = w1[k * 3 + c];
        }

    // ---- prefetch all 4 groups' gathers (col = lane&31 owns one column) ----
    const int col = lane & 31;
    float gxa[4], gya[4], gza[4];
#pragma unroll
    for (int g = 0; g < 4; ++g) {
        const int n = nbase + g * 8 + wave * 2 + (col >> 4);
        const int j = knn_idx[((size_t)bb * NPTS + n) * KK + (col & 15)];
        gxa[g] = xb[j * 3 + 0] - xb[n * 3 + 0];
        gya[g] = xb[j * 3 + 1] - xb[n * 3 + 1];
        gza[g] = xb[j * 3 + 2] - xb[n * 3 + 2];
    }
    __syncthreads();   // weights staged

    unsigned short* const cbH = cbh[wave];
    unsigned short* const cbL = cbl[wave];

#pragma unroll
    for (int g = 0; g < 4; ++g) {
        // ---- layer 1 in VALU -> layer-2 B-frags (h1 split hi/lo) ----
        bf16x8 b1h[2][2], b1l[2][2];               // [s][t]
#pragma unroll
        for (int t = 0; t < 2; ++t) {
            const int src = t * 16 + lq;
            const float sgx = __shfl(gxa[g], src);
            const float sgy = __shfl(gya[g], src);
            const float sgz = __shfl(gza[g], src);
#pragma unroll
            for (int s = 0; s < 2; ++s) {
                bf16x8 hh, ll;
#pragma unroll
                for (int j = 0; j < 8; ++j) {
                    float v = fmaf(w1v[s][j][2], sgz,
                              fmaf(w1v[s][j][1], sgy, w1v[s][j][0] * sgx));
                    v = fmaxf(v, 0.f);
                    hh[j] = (short)bhi(v);
                    ll[j] = (short)blo(v);
                }
                b1h[s][t] = hh; b1l[s][t] = ll;
            }
        }

        // ---- layer 2: acc[m][t] = W2 . h1 (split-bf16, 48 MFMA) ----
        f32x4 acc[4][2];
#pragma unroll
        for (int m = 0; m < 4; ++m)
#pragma unroll
            for (int t = 0; t < 2; ++t) acc[m][t] = (f32x4){0.f, 0.f, 0.f, 0.f};
#pragma unroll
        for (int m = 0; m < 4; ++m) {
            const int r = m * 16 + lq;
#pragma unroll
            for (int s = 0; s < 2; ++s) {
                const int byt = r * 128 + (((s * 4 + lg) ^ (r & 7)) << 4);
                const bf16x8 ah = *(const bf16x8*)((const char*)w2h + byt);
                const bf16x8 al = *(const bf16x8*)((const char*)w2l + byt);
#pragma unroll
                for (int t = 0; t < 2; ++t) {
                    acc[m][t] = __builtin_amdgcn_mfma_f32_16x16x32_bf16(ah, b1h[s][t], acc[m][t], 0, 0, 0);
                    acc[m][t] = __builtin_amdgcn_mfma_f32_16x16x32_bf16(ah, b1l[s][t], acc[m][t], 0, 0, 0);
                    acc[m][t] = __builtin_amdgcn_mfma_f32_16x16x32_bf16(al, b1h[s][t], acc[m][t], 0, 0, 0);
                }
            }
        }

        // ---- relu(h2) split/pack -> per-wave colbuf [col][k] ----
#pragma unroll
        for (int m = 0; m < 4; ++m)
#pragma unroll
            for (int t = 0; t < 2; ++t) {
                f32x4 v = acc[m][t];
#pragma unroll
                for (int e = 0; e < 4; ++e) v[e] = fmaxf(v[e], 0.f);
                const int co = t * 16 + lq;
                const int k0 = m * 16 + lg * 4;
                const int byt = co * 128 + (((k0 >> 3) ^ (co & 7)) << 4) + (k0 & 7) * 2;
                uint2 hw, lw;
                hw.x = pk2(bhi(v[0]), bhi(v[1])); hw.y = pk2(bhi(v[2]), bhi(v[3]));
                lw.x = pk2(blo(v[0]), blo(v[1])); lw.y = pk2(blo(v[2]), blo(v[3]));
                *(uint2*)((char*)cbH + byt) = hw;
                *(uint2*)((char*)cbL + byt) = lw;
            }

        // ---- layer 3 transposed: D[nb][c3] = h2^T . w3-col (48 MFMA) ----
        bf16x8 xh[2][2], xl[2][2];                 // h2 A-frags [s][t]
#pragma unroll
        for (int s = 0; s < 2; ++s)
#pragma unroll
            for (int t = 0; t < 2; ++t) {
                const int co = t * 16 + lq;
                const int byt = co * 128 + (((s * 4 + lg) ^ (co & 7)) << 4);
                xh[s][t] = *(const bf16x8*)((const char*)cbH + byt);
                xl[s][t] = *(const bf16x8*)((const char*)cbL + byt);
            }
        f32x4 acc3[4][2];
#pragma unroll
        for (int mb = 0; mb < 4; ++mb)
#pragma unroll
            for (int t = 0; t < 2; ++t) acc3[mb][t] = (f32x4){0.f, 0.f, 0.f, 0.f};
#pragma unroll
        for (int mb = 0; mb < 4; ++mb) {
            const int r = mb * 16 + lq;
#pragma unroll
            for (int s = 0; s < 2; ++s) {
                const int byt = r * 128 + (((s * 4 + lg) ^ (r & 7)) << 4);
                const bf16x8 wh = *(const bf16x8*)((const char*)w3h + byt);
                const bf16x8 wl = *(const bf16x8*)((const char*)w3l + byt);
#pragma unroll
                for (int t = 0; t < 2; ++t) {
                    acc3[mb][t] = __builtin_amdgcn_mfma_f32_16x16x32_bf16(xh[s][t], wh, acc3[mb][t], 0, 0, 0);
                    acc3[mb][t] = __builtin_amdgcn_mfma_f32_16x16x32_bf16(xh[s][t], wl, acc3[mb][t], 0, 0, 0);
                    acc3[mb][t] = __builtin_amdgcn_mfma_f32_16x16x32_bf16(xl[s][t], wh, acc3[mb][t], 0, 0, 0);
                }
            }
        }

        // ---- max over neighbors (rows): 3 v_max + 2 shfl ----
#pragma unroll
        for (int mb = 0; mb < 4; ++mb)
#pragma unroll
            for (int t = 0; t < 2; ++t) {
                float v = fmaxf(fmaxf(acc3[mb][t][0], acc3[mb][t][1]),
                                fmaxf(acc3[mb][t][2], acc3[mb][t][3]));
                v = fmaxf(v, __shfl_xor(v, 16));
                v = fmaxf(v, __shfl_xor(v, 32));
                if (lg == 0) obuf[mb * 16 + lq][g * 8 + wave * 2 + t] = v;
            }
    }
    __syncthreads();

    // ---- coalesced store: 64 rows x 32 pts, 32B per thread ----
    {
        const int c = tid >> 2, seg = tid & 3;
        const float4 v0 = *(const float4*)&obuf[c][seg * 8];
        const float4 v1 = *(const float4*)&obuf[c][seg * 8 + 4];
        float* op = &out[((size_t)(bb * CH + c)) * NPTS + nbase + seg * 8];
        *(float4*)op = v0;
        *(float4*)(op + 4) = v1;
    }
}

extern "C" void kernel_launch(void* const* d_in, const int* in_sizes, int n_in,
                              void* d_out, int out_size, void* d_ws, size_t ws_size,
                              hipStream_t stream) {
    (void)in_sizes; (void)n_in; (void)out_size; (void)ws_size;
    const float* xyz = (const float*)d_in[0];
    const float* w1  = (const float*)d_in[1];
    const float* w2  = (const float*)d_in[2];
    const float* w3  = (const float*)d_in[3];
    int*   knn = (int*)d_ws;                 // BATCH*NPTS*KK ints = 1 MiB
    float* out = (float*)d_out;

    knn_kernel<<<BATCH * NPTS / 32, 512, 0, stream>>>(xyz, knn);
    mlp_kernel<<<BATCH * NPTS / 32, 256, 0, stream>>>(xyz, knn, w1, w2, w3, out);
}

// Round 15
// 103.365 us; speedup vs baseline: 1.4015x; 1.0316x over previous
//
#include <hip/hip_runtime.h>
#include <hip/hip_bf16.h>

#define NPTS  4096
#define BATCH 4
#define KK    16
#define CH    64
#define SURV_CAP 40

typedef __attribute__((ext_vector_type(8))) short bf16x8;
typedef __attribute__((ext_vector_type(4))) float f32x4;

__device__ __forceinline__ unsigned short bhi(float x) {
    return (unsigned short)(__float_as_uint(x) >> 16);
}
__device__ __forceinline__ unsigned short blo(float x) {
    const float h = __uint_as_float(__float_as_uint(x) & 0xffff0000u);
    return (unsigned short)(__float_as_uint(x - h) >> 16);
}
// round-to-nearest-even bf16
__device__ __forceinline__ unsigned short brn(float x) {
    const unsigned u = __float_as_uint(x);
    return (unsigned short)((u + 0x7fffu + ((u >> 16) & 1u)) >> 16);
}
__device__ __forceinline__ unsigned pk2(unsigned short a, unsigned short b) {
    return (unsigned)a | ((unsigned)b << 16);
}

// Reference-rounded squared distance: (mul,mul,mul,add,add), NO contraction.
__device__ __forceinline__ float ref_dist(float px, float py, float pz,
                                          float qx, float qy, float qz) {
#pragma clang fp contract(off)
    const float dx = px - qx, dy = py - qy, dz = pz - qz;
    const float sx = dx * dx, sy = dy * dy, sz = dz * dz;
    return (sx + sy) + sz;
}

// ---------------------------------------------------------------------------
// Kernel A: exact KNN, 4 queries per wave, two-pass, atomic-append compact
// (UNCHANGED from round-14 passing version; ~30us, VALU 75%).
// ---------------------------------------------------------------------------
__global__ __launch_bounds__(512, 4) void knn_kernel(const float* __restrict__ xyz,
                                                     int* __restrict__ knn_idx) {
    __shared__ float2 sXY[NPTS];                    // 32 KB
    __shared__ float  sZ[NPTS];                     // 16 KB
    __shared__ int sidx[8][4][SURV_CAP];            // 5 KB survivor indices
    __shared__ int scnt[8][4];                      // per-wave survivor counts
    const int wave = threadIdx.x >> 6;
    const int lane = threadIdx.x & 63;
    const int q0 = blockIdx.x * 32 + wave * 4;      // queries q0..q0+3 (same batch)
    const int b = q0 >> 12;
    const int i0 = q0 & (NPTS - 1);
    const float* xb = xyz + (size_t)b * NPTS * 3;

#pragma unroll
    for (int r = 0; r < NPTS / 512; ++r) {
        const int pt = r * 512 + threadIdx.x;
        sXY[pt] = make_float2(xb[pt * 3 + 0], xb[pt * 3 + 1]);
        sZ[pt] = xb[pt * 3 + 2];
    }
    if (lane < 4) scnt[wave][lane] = 0;
    __syncthreads();

    float qx[4], qy[4], qz[4], ax[4], ay[4], az[4];
#pragma unroll
    for (int v = 0; v < 4; ++v) {
        const float2 t = sXY[i0 + v];
        qx[v] = t.x; qy[v] = t.y; qz[v] = sZ[i0 + v];
        ax[v] = -2.f * qx[v]; ay[v] = -2.f * qy[v]; az[v] = -2.f * qz[v];
    }

    float mn[4] = {3.4e38f, 3.4e38f, 3.4e38f, 3.4e38f};
#pragma unroll 8
    for (int t = 0; t < 64; ++t) {
        const float2 pxy = sXY[t * 64 + lane];
        const float pz = sZ[t * 64 + lane];
        const float px = pxy.x, py = pxy.y;
        const float w = fmaf(px, px, fmaf(py, py, pz * pz));
#pragma unroll
        for (int v = 0; v < 4; ++v) {
            const float s = fmaf(pz, az[v], fmaf(py, ay[v], fmaf(px, ax[v], w)));
            mn[v] = fminf(mn[v], s);
        }
    }

#pragma unroll
    for (int k = 2; k <= 64; k <<= 1) {
#pragma unroll
        for (int jj = k >> 1; jj > 0; jj >>= 1) {
            const bool tm = (((lane & jj) == 0) == ((lane & k) == 0));
#pragma unroll
            for (int v = 0; v < 4; ++v) {
                const float p = __shfl_xor(mn[v], jj);
                mn[v] = ((p < mn[v]) == tm) ? p : mn[v];
            }
        }
    }
    float T[4];
#pragma unroll
    for (int v = 0; v < 4; ++v) T[v] = __shfl(mn[v], 16) + 1e-3f;

#pragma unroll 4
    for (int t = 0; t < 64; ++t) {
        const float2 pxy = sXY[t * 64 + lane];
        const float pz = sZ[t * 64 + lane];
        const float px = pxy.x, py = pxy.y;
        const float w = fmaf(px, px, fmaf(py, py, pz * pz));
#pragma unroll
        for (int v = 0; v < 4; ++v) {
            const float s = fmaf(pz, az[v], fmaf(py, ay[v], fmaf(px, ax[v], w)));
            if (s <= T[v]) {
                const int slot = atomicAdd(&scnt[wave][v], 1);
                if (slot < SURV_CAP) sidx[wave][v][slot] = t * 64 + lane;
            }
        }
    }
    int cnt[4];
#pragma unroll
    for (int v = 0; v < 4; ++v) cnt[v] = scnt[wave][v];

    unsigned long long key[4];
#pragma unroll
    for (int v = 0; v < 4; ++v) {
        key[v] = ~0ull;
        if (lane < cnt[v] && cnt[v] <= SURV_CAP) {
            const int j = sidx[wave][v][lane];
            const float2 pxy = sXY[j];
            const float d = ref_dist(pxy.x, pxy.y, sZ[j], qx[v], qy[v], qz[v]);
            key[v] = ((unsigned long long)__float_as_uint(d) << 32) | (unsigned)j;
        }
    }

#pragma unroll
    for (int k = 2; k <= 64; k <<= 1) {
#pragma unroll
        for (int jj = k >> 1; jj > 0; jj >>= 1) {
            const bool tm = (((lane & jj) == 0) == ((lane & k) == 0));
#pragma unroll
            for (int v = 0; v < 4; ++v) {
                const unsigned long long p = __shfl_xor(key[v], jj);
                key[v] = ((p < key[v]) == tm) ? p : key[v];
            }
        }
    }

    auto fallback = [&](int q, float fqx, float fqy, float fqz) {
        float dp = -1.0f; int jp = -1;
        for (int pass = 0; pass < KK + 1; ++pass) {
            float dmin = 3.4e38f; int jmin = 0x7fffffff;
            for (int t = 0; t < 64; ++t) {
                const int j = t * 64 + lane;
                const float2 pxy = sXY[j];
                const float d = ref_dist(pxy.x, pxy.y, sZ[j], fqx, fqy, fqz);
                const bool valid = (d > dp) || (d == dp && j > jp);
                const bool less = valid && (d < dmin || (d == dmin && j < jmin));
                dmin = less ? d : dmin;
                jmin = less ? j : jmin;
            }
#pragma unroll
            for (int off = 32; off > 0; off >>= 1) {
                const float d2 = __shfl_xor(dmin, off);
                const int   j2 = __shfl_xor(jmin, off);
                if (d2 < dmin || (d2 == dmin && j2 < jmin)) { dmin = d2; jmin = j2; }
            }
            if (pass >= 1 && lane == 0) knn_idx[(size_t)q * KK + pass - 1] = jmin;
            dp = dmin; jp = jmin;
        }
    };

#pragma unroll
    for (int v = 0; v < 4; ++v) {
        if (cnt[v] <= SURV_CAP) {
            if (lane >= 1 && lane <= KK)
                knn_idx[(size_t)(q0 + v) * KK + lane - 1] = (int)(key[v] & 0xffffffffu);
        } else fallback(q0 + v, qx[v], qy[v], qz[v]);
    }
}

// ---------------------------------------------------------------------------
// Kernel B v6: MFMA MLP, reduced-precision + higher-TLP edition.
//  * h1 kept split (hi+lo, register-only, exact to 2^-17): layer2 input exact.
//  * W2/W3/h2 stored as ROUND-TO-NEAREST bf16 only (rel 2^-9, random-sign
//    accumulation over 64 terms -> ~1e-3 added absmax vs 5.16e-3 threshold).
//    MFMA/group 96 -> 48; weights LDS 32->16KB; colbuf 32->16KB.
//  * LDS ~37KB -> 4 blocks/CU by LDS; launch_bounds(256,3) caps VGPR at 170
//    (live ~140, no spill - R11 lesson) -> 3 blocks/CU resident.
//  * Grid 1024 blocks x 16 points (2 groups) so the ceiling is populated.
// ---------------------------------------------------------------------------
__global__ __launch_bounds__(256, 3) void mlp_kernel(const float* __restrict__ xyz,
                                                     const int* __restrict__ knn_idx,
                                                     const float* __restrict__ w1,
                                                     const float* __restrict__ w2,
                                                     const float* __restrict__ w3,
                                                     float* __restrict__ out) {
    __shared__ __align__(16) unsigned short w2b[64 * 64];   // 8 KB, RN bf16
    __shared__ __align__(16) unsigned short w3b[64 * 64];   // 8 KB
    __shared__ __align__(16) unsigned short cb[4][32 * 64]; // 16 KB h2 colbuf
    __shared__ __align__(16) float obuf[CH][20];            // 5.1 KB (16 pts + pad)

    const int tid = threadIdx.x;
    const int wave = tid >> 6, lane = tid & 63;
    const int lq = lane & 15, lg = lane >> 4;
    const int bx = blockIdx.x;
    const int bb = bx >> 8;                        // 256 blocks per batch
    const int nbase = (bx & 255) * 16;             // 16 points per block
    const float* xb = xyz + (size_t)bb * NPTS * 3;

    // ---- stage W2/W3 [64 rows][64 k] RN bf16, swizzle blk^(r&7) ----
    {
        const int r = tid >> 2, kb = (tid & 3) * 16;
#pragma unroll
        for (int kp = 0; kp < 16; kp += 2) {
            const int k = kb + kp;
            const int byt = r * 128 + (((k >> 3) ^ (r & 7)) << 4) + (k & 7) * 2;
            *(unsigned*)((char*)w2b + byt) = pk2(brn(w2[r * 64 + k]), brn(w2[r * 64 + k + 1]));
            *(unsigned*)((char*)w3b + byt) = pk2(brn(w3[r * 64 + k]), brn(w3[r * 64 + k + 1]));
        }
    }

    // ---- per-lane W1 rows for this lane's B-frag k-slots ----
    float w1v[2][8][3];
#pragma unroll
    for (int s = 0; s < 2; ++s)
#pragma unroll
        for (int j = 0; j < 8; ++j) {
            const int k = s * 32 + lg * 8 + j;
#pragma unroll
            for (int c = 0; c < 3; ++c) w1v[s][j][c] = w1[k * 3 + c];
        }

    // ---- prefetch both groups' gathers (col = lane&31 owns one column) ----
    const int col = lane & 31;
    float gxa[2], gya[2], gza[2];
#pragma unroll
    for (int g = 0; g < 2; ++g) {
        const int n = nbase + g * 8 + wave * 2 + (col >> 4);
        const int j = knn_idx[((size_t)bb * NPTS + n) * KK + (col & 15)];
        gxa[g] = xb[j * 3 + 0] - xb[n * 3 + 0];
        gya[g] = xb[j * 3 + 1] - xb[n * 3 + 1];
        gza[g] = xb[j * 3 + 2] - xb[n * 3 + 2];
    }
    __syncthreads();   // weights staged

    unsigned short* const cbW = cb[wave];

#pragma unroll
    for (int g = 0; g < 2; ++g) {
        // ---- layer 1 in VALU -> layer-2 B-frags (h1 split hi/lo, exact) ----
        bf16x8 b1h[2][2], b1l[2][2];               // [s][t]
#pragma unroll
        for (int t = 0; t < 2; ++t) {
            const int src = t * 16 + lq;
            const float sgx = __shfl(gxa[g], src);
            const float sgy = __shfl(gya[g], src);
            const float sgz = __shfl(gza[g], src);
#pragma unroll
            for (int s = 0; s < 2; ++s) {
                bf16x8 hh, ll;
#pragma unroll
                for (int j = 0; j < 8; ++j) {
                    float v = fmaf(w1v[s][j][2], sgz,
                              fmaf(w1v[s][j][1], sgy, w1v[s][j][0] * sgx));
                    v = fmaxf(v, 0.f);
                    hh[j] = (short)bhi(v);
                    ll[j] = (short)blo(v);
                }
                b1h[s][t] = hh; b1l[s][t] = ll;
            }
        }

        // ---- layer 2: acc[m][t] = W2 . h1 (32 MFMA) ----
        f32x4 acc[4][2];
#pragma unroll
        for (int m = 0; m < 4; ++m)
#pragma unroll
            for (int t = 0; t < 2; ++t) acc[m][t] = (f32x4){0.f, 0.f, 0.f, 0.f};
#pragma unroll
        for (int m = 0; m < 4; ++m) {
            const int r = m * 16 + lq;
#pragma unroll
            for (int s = 0; s < 2; ++s) {
                const int byt = r * 128 + (((s * 4 + lg) ^ (r & 7)) << 4);
                const bf16x8 ah = *(const bf16x8*)((const char*)w2b + byt);
#pragma unroll
                for (int t = 0; t < 2; ++t) {
                    acc[m][t] = __builtin_amdgcn_mfma_f32_16x16x32_bf16(ah, b1h[s][t], acc[m][t], 0, 0, 0);
                    acc[m][t] = __builtin_amdgcn_mfma_f32_16x16x32_bf16(ah, b1l[s][t], acc[m][t], 0, 0, 0);
                }
            }
        }

        // ---- relu(h2) RN-pack -> per-wave colbuf [col][k] ----
#pragma unroll
        for (int m = 0; m < 4; ++m)
#pragma unroll
            for (int t = 0; t < 2; ++t) {
                f32x4 v = acc[m][t];
#pragma unroll
                for (int e = 0; e < 4; ++e) v[e] = fmaxf(v[e], 0.f);
                const int co = t * 16 + lq;
                const int k0 = m * 16 + lg * 4;
                const int byt = co * 128 + (((k0 >> 3) ^ (co & 7)) << 4) + (k0 & 7) * 2;
                uint2 hw;
                hw.x = pk2(brn(v[0]), brn(v[1])); hw.y = pk2(brn(v[2]), brn(v[3]));
                *(uint2*)((char*)cbW + byt) = hw;
            }

        // ---- layer 3 transposed: D[nb][c3] = h2^T . w3-col (16 MFMA) ----
        bf16x8 xh[2][2];                           // h2 A-frags [s][t]
#pragma unroll
        for (int s = 0; s < 2; ++s)
#pragma unroll
            for (int t = 0; t < 2; ++t) {
                const int co = t * 16 + lq;
                const int byt = co * 128 + (((s * 4 + lg) ^ (co & 7)) << 4);
                xh[s][t] = *(const bf16x8*)((const char*)cbW + byt);
            }
        f32x4 acc3[4][2];
#pragma unroll
        for (int mb = 0; mb < 4; ++mb)
#pragma unroll
            for (int t = 0; t < 2; ++t) acc3[mb][t] = (f32x4){0.f, 0.f, 0.f, 0.f};
#pragma unroll
        for (int mb = 0; mb < 4; ++mb) {
            const int r = mb * 16 + lq;
#pragma unroll
            for (int s = 0; s < 2; ++s) {
                const int byt = r * 128 + (((s * 4 + lg) ^ (r & 7)) << 4);
                const bf16x8 wh = *(const bf16x8*)((const char*)w3b + byt);
#pragma unroll
                for (int t = 0; t < 2; ++t) {
                    acc3[mb][t] = __builtin_amdgcn_mfma_f32_16x16x32_bf16(xh[s][t], wh, acc3[mb][t], 0, 0, 0);
                }
            }
        }

        // ---- max over neighbors (rows): 3 v_max + 2 shfl ----
#pragma unroll
        for (int mb = 0; mb < 4; ++mb)
#pragma unroll
            for (int t = 0; t < 2; ++t) {
                float v = fmaxf(fmaxf(acc3[mb][t][0], acc3[mb][t][1]),
                                fmaxf(acc3[mb][t][2], acc3[mb][t][3]));
                v = fmaxf(v, __shfl_xor(v, 16));
                v = fmaxf(v, __shfl_xor(v, 32));
                if (lg == 0) obuf[mb * 16 + lq][g * 8 + wave * 2 + t] = v;
            }
    }
    __syncthreads();

    // ---- coalesced store: 64 rows x 16 pts, 16B per thread ----
    {
        const int c = tid >> 2, seg = tid & 3;
        const float4 v0 = *(const float4*)&obuf[c][seg * 4];
        *(float4*)&out[((size_t)(bb * CH + c)) * NPTS + nbase + seg * 4] = v0;
    }
}

extern "C" void kernel_launch(void* const* d_in, const int* in_sizes, int n_in,
                              void* d_out, int out_size, void* d_ws, size_t ws_size,
                              hipStream_t stream) {
    (void)in_sizes; (void)n_in; (void)out_size; (void)ws_size;
    const float* xyz = (const float*)d_in[0];
    const float* w1  = (const float*)d_in[1];
    const float* w2  = (const float*)d_in[2];
    const float* w3  = (const float*)d_in[3];
    int*   knn = (int*)d_ws;                 // BATCH*NPTS*KK ints = 1 MiB
    float* out = (float*)d_out;

    knn_kernel<<<BATCH * NPTS / 32, 512, 0, stream>>>(xyz, knn);
    mlp_kernel<<<BATCH * NPTS / 16, 256, 0, stream>>>(xyz, knn, w1, w2, w3, out);
}